// Round 6
// baseline (2538.025 us; speedup 1.0000x reference)
//
#include <hip/hip_runtime.h>
#include <hip/hip_bf16.h>

#define Bdim 64
#define Sdim 2048
#define Hdim 256

typedef __attribute__((ext_vector_type(8))) short short8;
typedef __attribute__((ext_vector_type(4))) float f32x4;

static __device__ __forceinline__ unsigned short f2bf(float f) {
  union { float f; unsigned int u; } v; v.f = f;
  unsigned int r = v.u + 0x7fffu + ((v.u >> 16) & 1u);  // RNE
  return (unsigned short)(r >> 16);
}
static __device__ __forceinline__ float bf2f(unsigned short u) {
  union { unsigned int u; float f; } v; v.u = ((unsigned int)u) << 16;
  return v.f;
}
static __device__ __forceinline__ float bflo(unsigned int u) {
  union { unsigned int u; float f; } v; v.u = u << 16; return v.f;
}
static __device__ __forceinline__ float bfhi(unsigned int u) {
  union { unsigned int u; float f; } v; v.u = u & 0xffff0000u; return v.f;
}

#if __has_builtin(__builtin_amdgcn_rcpf)
#define FAST_RCP(x) __builtin_amdgcn_rcpf(x)
#else
#define FAST_RCP(x) (1.0f / (x))
#endif

// tanh(x) = 1 - 2/(1 + e^{2x}) : mul, exp2, add, rcp, fma = 5 ops, no abs/copysign.
// x->+inf: exp2->inf, rcp->0 -> 1.  x->-inf: exp2->0, rcp(1)=1 -> -1.  Exact 0 at 0.
static __device__ __forceinline__ float tanh_fast(float x) {
  float e = exp2f(x * 2.8853900817779268f);  // e^{2x}
  return 1.0f - 2.0f * FAST_RCP(1.0f + e);
}

// ---------------------------------------------------------------------------
// Phase 2: sequential scan, MFMA, TRANSPOSED output (D = W_hh . h^T).
// 4 blocks x 512 threads (8 waves); block = 16 batches.
// W_hh held as per-wave register A-frags (identical per-lane packing to the
// verified gemm256 W operand); h read from LDS as B-frags (identical byte
// offsets to the verified A-read: row l15, 16B of consecutive k, XOR-swizzle).
// D lane layout (verified): col = lane&15 -> BATCH, row = g*4+e -> n.
// => per thread: batch l15, 4+4 consecutive n -> dwordx4 loads/stores,
//    ds_write_b64 via v_cvt_pk_bf16_f32. Depth-2 xw prefetch; lgkm-only
//    barrier per step (loads/stores stay in flight).
// ---------------------------------------------------------------------------
template<int XW_F32>
__global__ __launch_bounds__(512, 1) void rnn_scan_mfma(
    const void* __restrict__ xwp, const float* __restrict__ Whh,
    float* __restrict__ hout, float* __restrict__ hfin) {
  __shared__ __align__(16) unsigned short hbuf[2][16 * 256];  // 16 KiB
  const int tid = threadIdx.x;
  const int lane = tid & 63;
  const int wv = tid >> 6;     // wave 0..7 -> owns n-cols wv*32..wv*32+31
  const int l15 = lane & 15;   // = batch row (B-frag col) AND W-row selector (A-frag row)
  const int g = lane >> 4;     // 0..3
  const int bs = blockIdx.x * 16;

  for (int i = tid; i < 16 * 256; i += 512) hbuf[0][i] = 0;  // h0 = 0

  // A-frags (W_hh): lane (l15,g) holds W_hh[n][k], n = wv*32+tau*16+l15,
  // k = ks*32+g*8+e — byte-identical packing to gemm256's verified W operand.
  short8 wfrag[2][8];
#pragma unroll
  for (int tau = 0; tau < 2; ++tau) {
    int n = wv * 32 + tau * 16 + l15;
#pragma unroll
    for (int ks = 0; ks < 8; ++ks) {
      int k0 = ks * 32 + g * 8;
      const float* p = Whh + n * 256 + k0;
      short8 v;
#pragma unroll
      for (int e = 0; e < 8; ++e) v[e] = (short)f2bf(p[e]);
      wfrag[tau][ks] = v;
    }
  }

  // B-frag (h) LDS byte offsets: batch row = l15, kbyte = (ks*64+g*16) ^ ((l15&7)<<4)
  int aroff[8];
#pragma unroll
  for (int ks = 0; ks < 8; ++ks)
    aroff[ks] = l15 * 512 + ((ks * 64 + g * 16) ^ ((l15 & 7) << 4));

  // Per-thread output coords: batch m = l15 (global batch bs+l15),
  // n = wv*32 + tau*16 + g*4 + e  (e=0..3 CONSECUTIVE).
  const int nb0 = wv * 32 + g * 4;
  const int nb1 = nb0 + 16;
  const long rowbase = (long)(bs + l15) * Sdim * Hdim;  // [b][t][n] elements

  const float* xwf = (const float*)xwp;
  const unsigned short* xwh = (const unsigned short*)xwp;

  // LDS write byte offsets (next-step h): row = l15, byte 2n ^ ((l15&7)<<4);
  // 8B-aligned chunk, swizzle XORs bits>=4 -> chunk stays contiguous.
  const int wo0 = l15 * 512 + ((2 * nb0) ^ ((l15 & 7) << 4));
  const int wo1 = l15 * 512 + ((2 * nb1) ^ ((l15 & 7) << 4));

  // depth-2 xw prefetch buffers: A = even step, B = odd step
  f32x4 xwA0, xwA1, xwB0, xwB1;
  {
    long i0 = rowbase + nb0, i1 = rowbase + nb1;
    if (XW_F32) {
      xwA0 = *(const f32x4*)(xwf + i0);          xwA1 = *(const f32x4*)(xwf + i1);
      xwB0 = *(const f32x4*)(xwf + i0 + Hdim);   xwB1 = *(const f32x4*)(xwf + i1 + Hdim);
    } else {
      ushort4 a0 = *(const ushort4*)(xwh + i0), a1 = *(const ushort4*)(xwh + i1);
      ushort4 b0 = *(const ushort4*)(xwh + i0 + Hdim), b1 = *(const ushort4*)(xwh + i1 + Hdim);
      xwA0[0]=bf2f(a0.x); xwA0[1]=bf2f(a0.y); xwA0[2]=bf2f(a0.z); xwA0[3]=bf2f(a0.w);
      xwA1[0]=bf2f(a1.x); xwA1[1]=bf2f(a1.y); xwA1[2]=bf2f(a1.z); xwA1[3]=bf2f(a1.w);
      xwB0[0]=bf2f(b0.x); xwB0[1]=bf2f(b0.y); xwB0[2]=bf2f(b0.z); xwB0[3]=bf2f(b0.w);
      xwB1[0]=bf2f(b1.x); xwB1[1]=bf2f(b1.y); xwB1[2]=bf2f(b1.z); xwB1[3]=bf2f(b1.w);
    }
  }

  __syncthreads();  // h0 init visible (full drain once, outside the loop)

  int cb = 0;
  auto step = [&](int tc, f32x4& buf0, f32x4& buf1) {
    f32x4 acc0 = buf0, acc1 = buf1;  // C-init = xw_tc (folded add)

    // refill this buffer with xw for tc+2
    const long tn = (tc + 2 < Sdim) ? tc + 2 : Sdim - 1;
    {
      long i0 = rowbase + tn * Hdim + nb0, i1 = rowbase + tn * Hdim + nb1;
      if (XW_F32) {
        buf0 = *(const f32x4*)(xwf + i0);
        buf1 = *(const f32x4*)(xwf + i1);
      } else {
        ushort4 a0 = *(const ushort4*)(xwh + i0), a1 = *(const ushort4*)(xwh + i1);
        buf0[0]=bf2f(a0.x); buf0[1]=bf2f(a0.y); buf0[2]=bf2f(a0.z); buf0[3]=bf2f(a0.w);
        buf1[0]=bf2f(a1.x); buf1[1]=bf2f(a1.y); buf1[2]=bf2f(a1.z); buf1[3]=bf2f(a1.w);
      }
    }

    const char* hb = (const char*)hbuf[cb];
#pragma unroll
    for (int ks = 0; ks < 8; ++ks) {
      short8 b = *(const short8*)(hb + aroff[ks]);   // h as B operand
      acc0 = __builtin_amdgcn_mfma_f32_16x16x32_bf16(wfrag[0][ks], b, acc0, 0, 0, 0);
      acc1 = __builtin_amdgcn_mfma_f32_16x16x32_bf16(wfrag[1][ks], b, acc1, 0, 0, 0);
    }

    // epilogue: thread owns batch l15, n = nb0..+3 and nb1..+3
    char* hn = (char*)hbuf[cb ^ 1];
    f32x4 v0, v1;
#pragma unroll
    for (int e = 0; e < 4; ++e) v0[e] = tanh_fast(acc0[e]);
#pragma unroll
    for (int e = 0; e < 4; ++e) v1[e] = tanh_fast(acc1[e]);

    unsigned int p00, p01, p10, p11;
    asm("v_cvt_pk_bf16_f32 %0, %1, %2" : "=v"(p00) : "v"(v0[0]), "v"(v0[1]));
    asm("v_cvt_pk_bf16_f32 %0, %1, %2" : "=v"(p01) : "v"(v0[2]), "v"(v0[3]));
    asm("v_cvt_pk_bf16_f32 %0, %1, %2" : "=v"(p10) : "v"(v1[0]), "v"(v1[1]));
    asm("v_cvt_pk_bf16_f32 %0, %1, %2" : "=v"(p11) : "v"(v1[2]), "v"(v1[3]));
    *(uint2*)(hn + wo0) = make_uint2(p00, p01);     // ds_write_b64
    *(uint2*)(hn + wo1) = make_uint2(p10, p11);

    const long ob = rowbase + (long)tc * Hdim;
    *(f32x4*)(hout + ob + nb0) = v0;                // global_store_dwordx4
    *(f32x4*)(hout + ob + nb1) = v1;
    if (tc == Sdim - 1) {
      *(f32x4*)(hfin + (bs + l15) * Hdim + nb0) = v0;
      *(f32x4*)(hfin + (bs + l15) * Hdim + nb1) = v1;
    }

    // barrier WITHOUT vmcnt drain: only LDS ops must complete here.
    __builtin_amdgcn_sched_barrier(0);
    asm volatile("s_waitcnt lgkmcnt(0)" ::: "memory");
    __builtin_amdgcn_s_barrier();
    __builtin_amdgcn_sched_barrier(0);
    cb ^= 1;
  };

  for (int t = 0; t < Sdim; t += 2) {
    step(t, xwA0, xwA1);
    step(t + 1, xwB0, xwB1);
  }
}

// ---------------------------------------------------------------------------
// Fallback scan (no workspace): fused VALU version — known-good from round 3.
// ---------------------------------------------------------------------------
__global__ __launch_bounds__(256, 1) void rnn_scan_valu_fused(
    const float* __restrict__ x, const float* __restrict__ Wih,
    const float* __restrict__ bh, const float* __restrict__ Whh,
    float* __restrict__ hout, float* __restrict__ hfin) {
  __shared__ __align__(16) uint2 wt[64][256];
  __shared__ __align__(16) float hl[256];
  const int n = threadIdx.x;
  const int b = blockIdx.x;
  {
    const float2* src = (const float2*)Whh;
    unsigned int* w32 = (unsigned int*)wt;
    for (int i = n; i < 32768; i += 256) {
      float2 f = src[i];
      unsigned int u = (unsigned int)f2bf(f.x) | ((unsigned int)f2bf(f.y) << 16);
      int row = i >> 7, kk = i & 127, k4 = kk >> 1, half = kk & 1;
      w32[k4 * 512 + row * 2 + half] = u;
    }
  }
  hl[n] = 0.0f;
  __syncthreads();
  const long base = (long)b * Sdim * Hdim + n;
  for (int t = 0; t < Sdim; ++t) {
    const float* xr = x + ((long)b * Sdim + t) * 256;
    const float* wr = Wih + n * 256;
    float acc = bh[n];
    for (int k = 0; k < 256; ++k) acc += xr[k] * wr[k];
#pragma unroll 8
    for (int k4 = 0; k4 < 64; ++k4) {
      uint2 w2 = wt[k4][n];
      float4 h4 = *(const float4*)&hl[k4 * 4];
      acc += bflo(w2.x) * h4.x + bfhi(w2.x) * h4.y
           + bflo(w2.y) * h4.z + bfhi(w2.y) * h4.w;
    }
    float hv = tanh_fast(acc);
    __syncthreads();
    hl[n] = hv;
    hout[base + (long)t * Hdim] = hv;
    if (t == Sdim - 1) hfin[b * Hdim + n] = hv;
    __syncthreads();
  }
}

// ---------------------------------------------------------------------------
// Phases 1 & 3: out[r,n] = A[r,:] @ W[n,:] + bias[n], A is [131072,256].
// 512 thr (8 waves), 128 rows/block; W fully staged in STATIC LDS (bf16,
// XOR-swizzled). Phase 3 runs IN PLACE over d_out fp32->fp32 (each wave reads
// only the 16 rows it later writes; loads precede stores per-wave).
// ---------------------------------------------------------------------------
template<int A_F32, int OUT_F32>
__global__ __launch_bounds__(512, 2) void gemm256(const void* __restrict__ Ap,
                                                  const float* __restrict__ Wf,
                                                  const float* __restrict__ bias,
                                                  void* __restrict__ outp) {
  __shared__ __align__(16) char wl[131072];
  const int tid = threadIdx.x;
  const int lane = tid & 63;
  const int wv = tid >> 6;
  const int l15 = lane & 15;
  const int g = lane >> 4;
  const long r0 = (long)blockIdx.x * 128;

  for (int i = tid; i < 256 * 64; i += 512) {
    int n = i >> 6;
    int kc = (i & 63) * 4;
    f32x4 c = *(const f32x4*)(Wf + n * 256 + kc);
    unsigned int lo = (unsigned int)f2bf(c[0]) | ((unsigned int)f2bf(c[1]) << 16);
    unsigned int hi = (unsigned int)f2bf(c[2]) | ((unsigned int)f2bf(c[3]) << 16);
    int kb = (kc * 2) ^ ((n & 7) << 4);
    unsigned int* dst = (unsigned int*)(wl + n * 512 + kb);
    dst[0] = lo; dst[1] = hi;
  }
  __syncthreads();

  f32x4 acc[16];
#pragma unroll
  for (int tau = 0; tau < 16; ++tau) {
    float bv = bias[tau * 16 + l15];
    acc[tau][0] = bv; acc[tau][1] = bv; acc[tau][2] = bv; acc[tau][3] = bv;
  }

  const long arow = r0 + wv * 16 + l15;
#pragma unroll
  for (int ks = 0; ks < 8; ++ks) {
    const int k0 = ks * 32 + g * 8;
    short8 a;
    if (A_F32) {
      const f32x4* ap = (const f32x4*)((const float*)Ap + arow * 256 + k0);
      f32x4 x0 = ap[0], x1 = ap[1];
#pragma unroll
      for (int e = 0; e < 4; ++e) { a[e] = (short)f2bf(x0[e]); a[4 + e] = (short)f2bf(x1[e]); }
    } else {
      a = *(const short8*)((const unsigned short*)Ap + arow * 256 + k0);
    }
#pragma unroll
    for (int tau = 0; tau < 16; ++tau) {
      int n = tau * 16 + l15;
      int kb = (k0 * 2) ^ ((n & 7) << 4);
      short8 b = *(const short8*)(wl + n * 512 + kb);
      acc[tau] = __builtin_amdgcn_mfma_f32_16x16x32_bf16(a, b, acc[tau], 0, 0, 0);
    }
  }

#pragma unroll
  for (int tau = 0; tau < 16; ++tau) {
    int n = tau * 16 + l15;
#pragma unroll
    for (int e = 0; e < 4; ++e) {
      long row = r0 + wv * 16 + g * 4 + e;
      if (OUT_F32) ((float*)outp)[row * 256 + n] = acc[tau][e];
      else         ((unsigned short*)outp)[row * 256 + n] = f2bf(acc[tau][e]);
    }
  }
}

extern "C" void kernel_launch(void* const* d_in, const int* in_sizes, int n_in,
                              void* d_out, int out_size, void* d_ws, size_t ws_size,
                              hipStream_t stream) {
  const float* x    = (const float*)d_in[0];
  const float* W_ih = (const float*)d_in[1];
  const float* W_hh = (const float*)d_in[2];
  const float* b_h  = (const float*)d_in[3];
  const float* W_ho = (const float*)d_in[4];
  const float* b_o  = (const float*)d_in[5];
  float* out  = (float*)d_out;                              // fp32 output
  float* hout = out;                                        // h_t lives in outputs region
  float* hfin = out + (size_t)Bdim * Sdim * Hdim;           // h_final slot

  const int gblocks = (Bdim * Sdim) / 128;                  // 1024
  const size_t need32 = (size_t)Bdim * Sdim * Hdim * 4;     // 128 MiB
  const size_t need16 = need32 / 2;                         //  64 MiB

  if (ws_size >= need32) {
    gemm256<1, 1><<<gblocks, 512, 0, stream>>>(x, W_ih, b_h, d_ws);       // phase 1 (f32 xw)
    rnn_scan_mfma<1><<<4, 512, 0, stream>>>(d_ws, W_hh, hout, hfin);      // phase 2
  } else if (ws_size >= need16) {
    gemm256<1, 0><<<gblocks, 512, 0, stream>>>(x, W_ih, b_h, d_ws);       // phase 1 (bf16 xw)
    rnn_scan_mfma<0><<<4, 512, 0, stream>>>(d_ws, W_hh, hout, hfin);
  } else {
    rnn_scan_valu_fused<<<Bdim, 256, 0, stream>>>(x, W_ih, b_h, W_hh, hout, hfin);
  }
  // phase 3: in-place fp32 h -> fp32 outputs
  gemm256<1, 1><<<gblocks, 512, 0, stream>>>(hout, W_ho, b_o, out);
}

// Round 7
// 2398.647 us; speedup vs baseline: 1.0581x; 1.0581x over previous
//
#include <hip/hip_runtime.h>
#include <hip/hip_bf16.h>

#define Bdim 64
#define Sdim 2048
#define Hdim 256

typedef __attribute__((ext_vector_type(8))) short short8;
typedef __attribute__((ext_vector_type(4))) float f32x4;

static __device__ __forceinline__ unsigned short f2bf(float f) {
  union { float f; unsigned int u; } v; v.f = f;
  unsigned int r = v.u + 0x7fffu + ((v.u >> 16) & 1u);  // RNE
  return (unsigned short)(r >> 16);
}
static __device__ __forceinline__ float bf2f(unsigned short u) {
  union { unsigned int u; float f; } v; v.u = ((unsigned int)u) << 16;
  return v.f;
}
static __device__ __forceinline__ float bflo(unsigned int u) {
  union { unsigned int u; float f; } v; v.u = u << 16; return v.f;
}
static __device__ __forceinline__ float bfhi(unsigned int u) {
  union { unsigned int u; float f; } v; v.u = u & 0xffff0000u; return v.f;
}

#if __has_builtin(__builtin_amdgcn_rcpf)
#define FAST_RCP(x) __builtin_amdgcn_rcpf(x)
#else
#define FAST_RCP(x) (1.0f / (x))
#endif

// tanh(x) = 1 - 2/(1 + e^{2x}) : 5 ops, saturates correctly at +/-inf.
static __device__ __forceinline__ float tanh_fast(float x) {
  float e = exp2f(x * 2.8853900817779268f);  // e^{2x}
  return 1.0f - 2.0f * FAST_RCP(1.0f + e);
}

// ---------------------------------------------------------------------------
// Phase 2: sequential scan, MFMA, transposed (D = W_hh . h^T), 4 WAVES.
// 4 blocks x 256 threads; block = 16 batches; wave wv owns n-cols wv*64..+63
// (tau = 0..3). Each B-frag (h) ds_read_b128 is loaded ONCE and reused by 4
// A-frags (wfrag[tau]) -> LDS reads/step/CU halved vs the 8-wave version,
// putting LDS (~380 cyc) under the MFMA floor (~620 cyc = 128 MFMA x 4.85).
// All fragment packings / swizzle bytes / D-layout identical to the verified
// gemm256 conventions. Depth-2 xw prefetch; lgkm-only barrier per step.
// ---------------------------------------------------------------------------
template<int XW_F32>
__global__ __launch_bounds__(256, 1) void rnn_scan_mfma(
    const void* __restrict__ xwp, const float* __restrict__ Whh,
    float* __restrict__ hout, float* __restrict__ hfin) {
  __shared__ __align__(16) unsigned short hbuf[2][16 * 256];  // 16 KiB
  const int tid = threadIdx.x;
  const int lane = tid & 63;
  const int wv = tid >> 6;     // wave 0..3 -> owns n-cols wv*64..wv*64+63
  const int l15 = lane & 15;   // batch selector (D col) and W-row selector
  const int g = lane >> 4;     // 0..3
  const int bs = blockIdx.x * 16;

  for (int i = tid; i < 16 * 256; i += 256) hbuf[0][i] = 0;  // h0 = 0

  // A-frags (W_hh): lane (l15,g) holds W_hh[n][k], n = wv*64+tau*16+l15,
  // k = ks*32+g*8+e — same per-lane packing as gemm256's verified W operand.
  short8 wfrag[4][8];
#pragma unroll
  for (int tau = 0; tau < 4; ++tau) {
    int n = wv * 64 + tau * 16 + l15;
#pragma unroll
    for (int ks = 0; ks < 8; ++ks) {
      int k0 = ks * 32 + g * 8;
      const float* p = Whh + n * 256 + k0;
      short8 v;
#pragma unroll
      for (int e = 0; e < 8; ++e) v[e] = (short)f2bf(p[e]);
      wfrag[tau][ks] = v;
    }
  }

  // B-frag (h) LDS byte offsets: batch row = l15, kbyte = (ks*64+g*16) ^ swz
  int aroff[8];
#pragma unroll
  for (int ks = 0; ks < 8; ++ks)
    aroff[ks] = l15 * 512 + ((ks * 64 + g * 16) ^ ((l15 & 7) << 4));

  // Per-thread outputs: batch = bs+l15, n = wv*64 + tau*16 + g*4 + e (e=0..3)
  int nb[4], wo[4];
#pragma unroll
  for (int tau = 0; tau < 4; ++tau) {
    nb[tau] = wv * 64 + tau * 16 + g * 4;
    wo[tau] = l15 * 512 + ((2 * nb[tau]) ^ ((l15 & 7) << 4));
  }
  const long rowbase = (long)(bs + l15) * Sdim * Hdim;

  const float* xwf = (const float*)xwp;
  const unsigned short* xwh = (const unsigned short*)xwp;

  auto ldxw = [&](long idx) -> f32x4 {
    if (XW_F32) return *(const f32x4*)(xwf + idx);
    ushort4 a = *(const ushort4*)(xwh + idx);
    f32x4 r; r[0]=bf2f(a.x); r[1]=bf2f(a.y); r[2]=bf2f(a.z); r[3]=bf2f(a.w);
    return r;
  };

  // depth-2 xw prefetch buffers (always indexed by unrolled constants)
  f32x4 bufA[4], bufB[4];
#pragma unroll
  for (int tau = 0; tau < 4; ++tau) {
    bufA[tau] = ldxw(rowbase + nb[tau]);
    bufB[tau] = ldxw(rowbase + Hdim + nb[tau]);
  }

  __syncthreads();  // h0 visible (single full drain, outside the loop)

  int cb = 0;
  auto step = [&](int tc, f32x4 (&buf)[4]) {
    f32x4 acc[4];
#pragma unroll
    for (int tau = 0; tau < 4; ++tau) acc[tau] = buf[tau];  // C-init = xw_tc

    // refill buffer with xw for tc+2 (stays in flight across barriers)
    const long tn = (tc + 2 < Sdim) ? tc + 2 : Sdim - 1;
#pragma unroll
    for (int tau = 0; tau < 4; ++tau)
      buf[tau] = ldxw(rowbase + tn * Hdim + nb[tau]);

    // 8 ds_read_b128, each reused by 4 MFMA chains (tau-interleaved)
    const char* hb = (const char*)hbuf[cb];
#pragma unroll
    for (int ks = 0; ks < 8; ++ks) {
      short8 h8 = *(const short8*)(hb + aroff[ks]);
#pragma unroll
      for (int tau = 0; tau < 4; ++tau)
        acc[tau] = __builtin_amdgcn_mfma_f32_16x16x32_bf16(wfrag[tau][ks], h8, acc[tau], 0, 0, 0);
    }

    // epilogue: tanh, pack to bf16 for next-step LDS, fp32 stream to hout
    char* hn = (char*)hbuf[cb ^ 1];
    const long ob = rowbase + (long)tc * Hdim;
#pragma unroll
    for (int tau = 0; tau < 4; ++tau) {
      f32x4 v;
#pragma unroll
      for (int e = 0; e < 4; ++e) v[e] = tanh_fast(acc[tau][e]);
      unsigned int plo, phi;
      asm("v_cvt_pk_bf16_f32 %0, %1, %2" : "=v"(plo) : "v"(v[0]), "v"(v[1]));
      asm("v_cvt_pk_bf16_f32 %0, %1, %2" : "=v"(phi) : "v"(v[2]), "v"(v[3]));
      *(uint2*)(hn + wo[tau]) = make_uint2(plo, phi);   // ds_write_b64
      *(f32x4*)(hout + ob + nb[tau]) = v;               // global_store_dwordx4
      if (tc == Sdim - 1) *(f32x4*)(hfin + (bs + l15) * Hdim + nb[tau]) = v;
    }

    // barrier WITHOUT vmcnt drain: only LDS ops must complete here.
    __builtin_amdgcn_sched_barrier(0);
    asm volatile("s_waitcnt lgkmcnt(0)" ::: "memory");
    __builtin_amdgcn_s_barrier();
    __builtin_amdgcn_sched_barrier(0);
    cb ^= 1;
  };

  for (int t = 0; t < Sdim; t += 2) {
    step(t, bufA);
    step(t + 1, bufB);
  }
}

// ---------------------------------------------------------------------------
// Fallback scan (no workspace): fused VALU version — known-good from round 3.
// ---------------------------------------------------------------------------
__global__ __launch_bounds__(256, 1) void rnn_scan_valu_fused(
    const float* __restrict__ x, const float* __restrict__ Wih,
    const float* __restrict__ bh, const float* __restrict__ Whh,
    float* __restrict__ hout, float* __restrict__ hfin) {
  __shared__ __align__(16) uint2 wt[64][256];
  __shared__ __align__(16) float hl[256];
  const int n = threadIdx.x;
  const int b = blockIdx.x;
  {
    const float2* src = (const float2*)Whh;
    unsigned int* w32 = (unsigned int*)wt;
    for (int i = n; i < 32768; i += 256) {
      float2 f = src[i];
      unsigned int u = (unsigned int)f2bf(f.x) | ((unsigned int)f2bf(f.y) << 16);
      int row = i >> 7, kk = i & 127, k4 = kk >> 1, half = kk & 1;
      w32[k4 * 512 + row * 2 + half] = u;
    }
  }
  hl[n] = 0.0f;
  __syncthreads();
  const long base = (long)b * Sdim * Hdim + n;
  for (int t = 0; t < Sdim; ++t) {
    const float* xr = x + ((long)b * Sdim + t) * 256;
    const float* wr = Wih + n * 256;
    float acc = bh[n];
    for (int k = 0; k < 256; ++k) acc += xr[k] * wr[k];
#pragma unroll 8
    for (int k4 = 0; k4 < 64; ++k4) {
      uint2 w2 = wt[k4][n];
      float4 h4 = *(const float4*)&hl[k4 * 4];
      acc += bflo(w2.x) * h4.x + bfhi(w2.x) * h4.y
           + bflo(w2.y) * h4.z + bfhi(w2.y) * h4.w;
    }
    float hv = tanh_fast(acc);
    __syncthreads();
    hl[n] = hv;
    hout[base + (long)t * Hdim] = hv;
    if (t == Sdim - 1) hfin[b * Hdim + n] = hv;
    __syncthreads();
  }
}

// ---------------------------------------------------------------------------
// Phases 1 & 3: out[r,n] = A[r,:] @ W[n,:] + bias[n], A is [131072,256].
// 512 thr (8 waves), 128 rows/block; W fully staged in STATIC LDS (bf16,
// XOR-swizzled). Phase 3 runs IN PLACE over d_out fp32->fp32 (each wave reads
// only the 16 rows it later writes; loads precede stores per-wave).
// ---------------------------------------------------------------------------
template<int A_F32, int OUT_F32>
__global__ __launch_bounds__(512, 2) void gemm256(const void* __restrict__ Ap,
                                                  const float* __restrict__ Wf,
                                                  const float* __restrict__ bias,
                                                  void* __restrict__ outp) {
  __shared__ __align__(16) char wl[131072];
  const int tid = threadIdx.x;
  const int lane = tid & 63;
  const int wv = tid >> 6;
  const int l15 = lane & 15;
  const int g = lane >> 4;
  const long r0 = (long)blockIdx.x * 128;

  for (int i = tid; i < 256 * 64; i += 512) {
    int n = i >> 6;
    int kc = (i & 63) * 4;
    f32x4 c = *(const f32x4*)(Wf + n * 256 + kc);
    unsigned int lo = (unsigned int)f2bf(c[0]) | ((unsigned int)f2bf(c[1]) << 16);
    unsigned int hi = (unsigned int)f2bf(c[2]) | ((unsigned int)f2bf(c[3]) << 16);
    int kb = (kc * 2) ^ ((n & 7) << 4);
    unsigned int* dst = (unsigned int*)(wl + n * 512 + kb);
    dst[0] = lo; dst[1] = hi;
  }
  __syncthreads();

  f32x4 acc[16];
#pragma unroll
  for (int tau = 0; tau < 16; ++tau) {
    float bv = bias[tau * 16 + l15];
    acc[tau][0] = bv; acc[tau][1] = bv; acc[tau][2] = bv; acc[tau][3] = bv;
  }

  const long arow = r0 + wv * 16 + l15;
#pragma unroll
  for (int ks = 0; ks < 8; ++ks) {
    const int k0 = ks * 32 + g * 8;
    short8 a;
    if (A_F32) {
      const f32x4* ap = (const f32x4*)((const float*)Ap + arow * 256 + k0);
      f32x4 x0 = ap[0], x1 = ap[1];
#pragma unroll
      for (int e = 0; e < 4; ++e) { a[e] = (short)f2bf(x0[e]); a[4 + e] = (short)f2bf(x1[e]); }
    } else {
      a = *(const short8*)((const unsigned short*)Ap + arow * 256 + k0);
    }
#pragma unroll
    for (int tau = 0; tau < 16; ++tau) {
      int n = tau * 16 + l15;
      int kb = (k0 * 2) ^ ((n & 7) << 4);
      short8 b = *(const short8*)(wl + n * 512 + kb);
      acc[tau] = __builtin_amdgcn_mfma_f32_16x16x32_bf16(a, b, acc[tau], 0, 0, 0);
    }
  }

#pragma unroll
  for (int tau = 0; tau < 16; ++tau) {
    int n = tau * 16 + l15;
#pragma unroll
    for (int e = 0; e < 4; ++e) {
      long row = r0 + wv * 16 + g * 4 + e;
      if (OUT_F32) ((float*)outp)[row * 256 + n] = acc[tau][e];
      else         ((unsigned short*)outp)[row * 256 + n] = f2bf(acc[tau][e]);
    }
  }
}

extern "C" void kernel_launch(void* const* d_in, const int* in_sizes, int n_in,
                              void* d_out, int out_size, void* d_ws, size_t ws_size,
                              hipStream_t stream) {
  const float* x    = (const float*)d_in[0];
  const float* W_ih = (const float*)d_in[1];
  const float* W_hh = (const float*)d_in[2];
  const float* b_h  = (const float*)d_in[3];
  const float* W_ho = (const float*)d_in[4];
  const float* b_o  = (const float*)d_in[5];
  float* out  = (float*)d_out;                              // fp32 output
  float* hout = out;                                        // h_t lives in outputs region
  float* hfin = out + (size_t)Bdim * Sdim * Hdim;           // h_final slot

  const int gblocks = (Bdim * Sdim) / 128;                  // 1024
  const size_t need32 = (size_t)Bdim * Sdim * Hdim * 4;     // 128 MiB
  const size_t need16 = need32 / 2;                         //  64 MiB

  if (ws_size >= need32) {
    gemm256<1, 1><<<gblocks, 512, 0, stream>>>(x, W_ih, b_h, d_ws);       // phase 1 (f32 xw)
    rnn_scan_mfma<1><<<4, 256, 0, stream>>>(d_ws, W_hh, hout, hfin);      // phase 2
  } else if (ws_size >= need16) {
    gemm256<1, 0><<<gblocks, 512, 0, stream>>>(x, W_ih, b_h, d_ws);       // phase 1 (bf16 xw)
    rnn_scan_mfma<0><<<4, 256, 0, stream>>>(d_ws, W_hh, hout, hfin);
  } else {
    rnn_scan_valu_fused<<<Bdim, 256, 0, stream>>>(x, W_ih, b_h, W_hh, hout, hfin);
  }
  // phase 3: in-place fp32 h -> fp32 outputs
  gemm256<1, 1><<<gblocks, 512, 0, stream>>>(hout, W_ho, b_o, out);
}